// Round 18
// baseline (595.448 us; speedup 1.0000x reference)
//
#include <hip/hip_runtime.h>
#include <hip/hip_bf16.h>

#define N_NODES   50000
#define N_EDGES   800000
#define NUM_GRAPHS 256
#define IN_DIM    128
#define HD        64
#define EPS       1e-5f
#define SCAN_NB   196      // ceil(50000/256)

typedef __hip_bfloat16 bf16;

// ---------------- diagnostics ----------------
__global__ void k_diag(float* __restrict__ out, int n, float v) {
    int t = blockIdx.x * 256 + threadIdx.x;
    if (t < n) out[t] = v;
}

// ---------------- CSR build ----------------
__global__ void k_count(const int* __restrict__ dst, int* __restrict__ cnti,
                        int* __restrict__ pos) {
    int e = blockIdx.x * 256 + threadIdx.x;
    if (e < N_EDGES) pos[e] = atomicAdd(&cnti[dst[e]], 1);
}

__global__ void k_scan1(const int* __restrict__ cnti, int* __restrict__ off,
                        int* __restrict__ bsum) {
    __shared__ int wsum[4];
    int idx = blockIdx.x * 256 + threadIdx.x;
    int lane = threadIdx.x & 63, wid = threadIdx.x >> 6;
    int v = (idx < N_NODES) ? cnti[idx] : 0;
    int s = v;
    #pragma unroll
    for (int o = 1; o < 64; o <<= 1) {
        int u = __shfl_up(s, o);
        if (lane >= o) s += u;
    }
    if (lane == 63) wsum[wid] = s;
    __syncthreads();
    int wbase = 0;
    #pragma unroll
    for (int w = 0; w < 4; w++) wbase += (w < wid) ? wsum[w] : 0;
    if (idx < N_NODES) off[idx] = wbase + s - v;
    if (threadIdx.x == 255) bsum[blockIdx.x] = wbase + s;
}

__global__ void k_scan3(int* __restrict__ off, const int* __restrict__ bsum) {
    __shared__ int wsum[4];
    __shared__ int spre;
    int lane = threadIdx.x & 63, wid = threadIdx.x >> 6;
    int v = (threadIdx.x < blockIdx.x) ? bsum[threadIdx.x] : 0;
    #pragma unroll
    for (int o = 32; o > 0; o >>= 1) v += __shfl_down(v, o);
    if (lane == 0) wsum[wid] = v;
    __syncthreads();
    if (threadIdx.x == 0) spre = wsum[0] + wsum[1] + wsum[2] + wsum[3];
    __syncthreads();
    int pre = spre;
    int idx = blockIdx.x * 256 + threadIdx.x;
    if (idx < N_NODES) off[idx] += pre;
    else if (idx == N_NODES) off[N_NODES] = N_EDGES;
}

__global__ void k_fill(const int* __restrict__ src, const int* __restrict__ dst,
                       const int* __restrict__ off, const int* __restrict__ pos,
                       int* __restrict__ nbr) {
    int e = blockIdx.x * 256 + threadIdx.x;
    if (e >= N_EDGES) return;
    int d = dst[e];
    nbr[off[d] + pos[e]] = src[e];
}

// ---- fused transform, LDS-staged X tile: B(bf16) = X@Wl ; C = X@Wr + bl ----
template <int K>
__global__ __launch_bounds__(256) void k_xform3(
        const float* __restrict__ X, const float* __restrict__ Wl,
        const float* __restrict__ Wr, const float* __restrict__ bl,
        bf16* __restrict__ B, float* __restrict__ C) {
    __shared__ float tile[32 * K];
    const int NPW = 8;
    int nodes0 = blockIdx.x * 32;
    {
        const int total4 = 32 * K / 4;
        int nmax4 = (N_NODES - nodes0) * K / 4;
        const float4* Xg = (const float4*)(X + (long)nodes0 * K);
        float4* tg = (float4*)tile;
        for (int idx = threadIdx.x; idx < total4; idx += 256) {
            float4 v = make_float4(0.f, 0.f, 0.f, 0.f);
            if (idx < nmax4) v = Xg[idx];
            tg[idx] = v;
        }
    }
    __syncthreads();
    int wave = threadIdx.x >> 6, j = threadIdx.x & 63;
    long base = (long)nodes0 + wave * NPW;
    if (base >= N_NODES) return;
    float accB[NPW], accC[NPW];
    #pragma unroll
    for (int n = 0; n < NPW; n++) { accB[n] = 0.f; accC[n] = 0.f; }
    const float* Xs = tile + (wave * NPW) * K;
    for (int kc = 0; kc < K; kc += 4) {
        float wl0 = Wl[(kc + 0) * HD + j], wr0 = Wr[(kc + 0) * HD + j];
        float wl1 = Wl[(kc + 1) * HD + j], wr1 = Wr[(kc + 1) * HD + j];
        float wl2 = Wl[(kc + 2) * HD + j], wr2 = Wr[(kc + 2) * HD + j];
        float wl3 = Wl[(kc + 3) * HD + j], wr3 = Wr[(kc + 3) * HD + j];
        #pragma unroll
        for (int n = 0; n < NPW; n++) {
            float4 xv = *(const float4*)(Xs + n * K + kc);
            accB[n] = fmaf(xv.x, wl0, accB[n]);
            accC[n] = fmaf(xv.x, wr0, accC[n]);
            accB[n] = fmaf(xv.y, wl1, accB[n]);
            accC[n] = fmaf(xv.y, wr1, accC[n]);
            accB[n] = fmaf(xv.z, wl2, accB[n]);
            accC[n] = fmaf(xv.z, wr2, accC[n]);
            accB[n] = fmaf(xv.w, wl3, accB[n]);
            accC[n] = fmaf(xv.w, wr3, accC[n]);
        }
    }
    float bb = bl[j];
    int nact = (int)min((long)NPW, (long)N_NODES - base);
    for (int n = 0; n < nact; n++) {
        long i = base + n;
        B[i * HD + j] = __float2bfloat16(accB[n]);
        C[i * HD + j] = accC[n] + bb;
    }
}

// ---- CSR gather (bf16 messages): C[i,:] += mean_{s in nbr(i)} B[s,:] ----
__global__ void k_gather(const int* __restrict__ off, const int* __restrict__ nbr,
                         const bf16* __restrict__ B, float* __restrict__ C) {
    int t = blockIdx.x * 256 + threadIdx.x;
    int i = t >> 6, j = t & 63;
    if (i >= N_NODES) return;
    int beg = off[i], end = off[i + 1];
    float s0 = 0.f, s1 = 0.f, s2 = 0.f, s3 = 0.f;
    float s4 = 0.f, s5 = 0.f, s6 = 0.f, s7 = 0.f;
    float s8 = 0.f, s9 = 0.f, sA = 0.f, sB2 = 0.f;
    float sC = 0.f, sD = 0.f, sE = 0.f, sF = 0.f;
    for (int base = beg; base < end; base += 64) {
        int idx = base + j;
        int nv = (idx < end) ? nbr[idx] : 0;
        int m = min(64, end - base);
        int tt = 0;
        for (; tt + 16 <= m; tt += 16) {
            int n0 = __shfl(nv, tt + 0);
            int n1 = __shfl(nv, tt + 1);
            int n2 = __shfl(nv, tt + 2);
            int n3 = __shfl(nv, tt + 3);
            int n4 = __shfl(nv, tt + 4);
            int n5 = __shfl(nv, tt + 5);
            int n6 = __shfl(nv, tt + 6);
            int n7 = __shfl(nv, tt + 7);
            int n8 = __shfl(nv, tt + 8);
            int n9 = __shfl(nv, tt + 9);
            int nA = __shfl(nv, tt + 10);
            int nB = __shfl(nv, tt + 11);
            int nC = __shfl(nv, tt + 12);
            int nD = __shfl(nv, tt + 13);
            int nE = __shfl(nv, tt + 14);
            int nF = __shfl(nv, tt + 15);
            s0 += __bfloat162float(B[(long)n0 * HD + j]);
            s1 += __bfloat162float(B[(long)n1 * HD + j]);
            s2 += __bfloat162float(B[(long)n2 * HD + j]);
            s3 += __bfloat162float(B[(long)n3 * HD + j]);
            s4 += __bfloat162float(B[(long)n4 * HD + j]);
            s5 += __bfloat162float(B[(long)n5 * HD + j]);
            s6 += __bfloat162float(B[(long)n6 * HD + j]);
            s7 += __bfloat162float(B[(long)n7 * HD + j]);
            s8 += __bfloat162float(B[(long)n8 * HD + j]);
            s9 += __bfloat162float(B[(long)n9 * HD + j]);
            sA += __bfloat162float(B[(long)nA * HD + j]);
            sB2 += __bfloat162float(B[(long)nB * HD + j]);
            sC += __bfloat162float(B[(long)nC * HD + j]);
            sD += __bfloat162float(B[(long)nD * HD + j]);
            sE += __bfloat162float(B[(long)nE * HD + j]);
            sF += __bfloat162float(B[(long)nF * HD + j]);
        }
        for (; tt + 4 <= m; tt += 4) {
            int n0 = __shfl(nv, tt + 0);
            int n1 = __shfl(nv, tt + 1);
            int n2 = __shfl(nv, tt + 2);
            int n3 = __shfl(nv, tt + 3);
            s0 += __bfloat162float(B[(long)n0 * HD + j]);
            s1 += __bfloat162float(B[(long)n1 * HD + j]);
            s2 += __bfloat162float(B[(long)n2 * HD + j]);
            s3 += __bfloat162float(B[(long)n3 * HD + j]);
        }
        for (; tt < m; ++tt) {
            int nb = __shfl(nv, tt);
            s0 += __bfloat162float(B[(long)nb * HD + j]);
        }
    }
    int deg = end - beg;
    float inv = 1.0f / (float)max(deg, 1);
    float sum = ((s0 + s1) + (s2 + s3)) + ((s4 + s5) + (s6 + s7))
              + ((s8 + s9) + (sA + sB2)) + ((sC + sD) + (sE + sF));
    C[(long)i * HD + j] += sum * inv;
}

// ---- global mean pool (bounds found in-block; sorted batch) ----
__global__ void k_pool2(const int* __restrict__ batch, const float* __restrict__ h,
                        float* __restrict__ cb) {
    __shared__ float red[4][64];
    __shared__ int sb[2];
    int g = blockIdx.x;
    if (threadIdx.x < 2) {
        int gq = g + threadIdx.x;
        int lo = 0, hi = N_NODES;
        while (lo < hi) {
            int mid = (lo + hi) >> 1;
            if (batch[mid] < gq) lo = mid + 1; else hi = mid;
        }
        sb[threadIdx.x] = lo;
    }
    __syncthreads();
    int beg = sb[0], end = sb[1];
    int j = threadIdx.x & 63, r = threadIdx.x >> 6;
    float s = 0.f;
    for (int n = beg + r; n < end; n += 4) s += h[(long)n * HD + j];
    red[r][j] = s;
    __syncthreads();
    if (r == 0) {
        float tot = (red[0][j] + red[1][j]) + (red[2][j] + red[3][j]);
        int cnt = end - beg;
        cb[g * HD + j] = tot / (float)max(cnt, 1);
    }
}

// ---- fused linear + BN + tanh: block = 1024 (64 cols x 16 rowgroups) ----
// thread (jj, rg) computes rows r = rg + 16t, t=0..15 -> vals[16] (~30 VGPR, no spill)
template <int N, int K>
__global__ __launch_bounds__(1024) void k_linbn(
        const float* __restrict__ A, const float* __restrict__ W,
        const float* __restrict__ b, const float* __restrict__ g,
        const float* __restrict__ be, float* __restrict__ out) {
    __shared__ float ssum[16][64], ssq[16][64], sm[64], ssc[64];
    int jj = threadIdx.x & 63, rg = threadIdx.x >> 6;   // rg in 0..15
    int j = blockIdx.x * 64 + jj;
    float vals[16];
    float bj = b[j];
    #pragma unroll
    for (int t = 0; t < 16; t++) vals[t] = bj;
    for (int k = 0; k < K; k += 4) {
        float w0 = W[(k + 0) * N + j];
        float w1 = W[(k + 1) * N + j];
        float w2 = W[(k + 2) * N + j];
        float w3 = W[(k + 3) * N + j];
        #pragma unroll
        for (int t = 0; t < 16; t++) {
            int r = rg + 16 * t;
            float4 a = *(const float4*)(A + r * K + k);
            vals[t] = fmaf(a.x, w0, vals[t]);
            vals[t] = fmaf(a.y, w1, vals[t]);
            vals[t] = fmaf(a.z, w2, vals[t]);
            vals[t] = fmaf(a.w, w3, vals[t]);
        }
    }
    float sum = 0.f, sq = 0.f;
    #pragma unroll
    for (int t = 0; t < 16; t++) { sum += vals[t]; sq += vals[t] * vals[t]; }
    ssum[rg][jj] = sum; ssq[rg][jj] = sq;
    __syncthreads();
    if (rg == 0) {
        float S = 0.f, Q = 0.f;
        #pragma unroll
        for (int r = 0; r < 16; r++) { S += ssum[r][jj]; Q += ssq[r][jj]; }
        float mean = S * (1.0f / NUM_GRAPHS);
        float var = Q * (1.0f / NUM_GRAPHS) - mean * mean;
        sm[jj] = mean;
        ssc[jj] = rsqrtf(fmaxf(var, 0.f) + EPS) * g[j];
    }
    __syncthreads();
    float mean = sm[jj], sc = ssc[jj], sh = be[j];
    #pragma unroll
    for (int t = 0; t < 16; t++) {
        out[(rg + 16 * t) * N + j] = tanhf((vals[t] - mean) * sc + sh);
    }
}

// ---- lin3(128->64)+BN+tanh + lin4(64->10) fused, single 1024-thread block ----
__global__ __launch_bounds__(1024) void k_linbn3f(
        const float* __restrict__ A, const float* __restrict__ W,
        const float* __restrict__ b, const float* __restrict__ g,
        const float* __restrict__ be,
        const float* __restrict__ w4, const float* __restrict__ b4,
        float* __restrict__ out) {
    const int K = 128, N = 64;
    __shared__ float ssum[16][64], ssq[16][64], sm[64], ssc[64];
    __shared__ float m3s[256 * 65];     // padded rows: conflict-free row reads
    int jj = threadIdx.x & 63, rg = threadIdx.x >> 6;
    int j = jj;
    float vals[16];
    float bj = b[j];
    #pragma unroll
    for (int t = 0; t < 16; t++) vals[t] = bj;
    for (int k = 0; k < K; k += 4) {
        float w0 = W[(k + 0) * N + j];
        float w1 = W[(k + 1) * N + j];
        float w2 = W[(k + 2) * N + j];
        float w3 = W[(k + 3) * N + j];
        #pragma unroll
        for (int t = 0; t < 16; t++) {
            int r = rg + 16 * t;
            float4 a = *(const float4*)(A + r * K + k);
            vals[t] = fmaf(a.x, w0, vals[t]);
            vals[t] = fmaf(a.y, w1, vals[t]);
            vals[t] = fmaf(a.z, w2, vals[t]);
            vals[t] = fmaf(a.w, w3, vals[t]);
        }
    }
    float sum = 0.f, sq = 0.f;
    #pragma unroll
    for (int t = 0; t < 16; t++) { sum += vals[t]; sq += vals[t] * vals[t]; }
    ssum[rg][jj] = sum; ssq[rg][jj] = sq;
    __syncthreads();
    if (rg == 0) {
        float S = 0.f, Q = 0.f;
        #pragma unroll
        for (int r = 0; r < 16; r++) { S += ssum[r][jj]; Q += ssq[r][jj]; }
        float mean = S * (1.0f / NUM_GRAPHS);
        float var = Q * (1.0f / NUM_GRAPHS) - mean * mean;
        sm[jj] = mean;
        ssc[jj] = rsqrtf(fmaxf(var, 0.f) + EPS) * g[j];
    }
    __syncthreads();
    float mean = sm[jj], sc = ssc[jj], sh = be[j];
    #pragma unroll
    for (int t = 0; t < 16; t++) {
        m3s[(rg + 16 * t) * 65 + jj] = tanhf((vals[t] - mean) * sc + sh);
    }
    __syncthreads();
    // lin4: thread i<256 computes row i's 10 outputs from LDS
    int i = threadIdx.x;
    if (i < NUM_GRAPHS) {
        const float* row = m3s + i * 65;
        #pragma unroll
        for (int jf = 0; jf < 10; jf++) {
            float s = b4[jf];
            #pragma unroll
            for (int k = 0; k < 64; k++) s = fmaf(row[k], w4[k * 10 + jf], s);
            out[i * 10 + jf] = s;
        }
    }
}

extern "C" void kernel_launch(void* const* d_in, const int* in_sizes, int n_in,
                              void* d_out, int out_size, void* d_ws, size_t ws_size,
                              hipStream_t stream) {
    const float* x     = (const float*)d_in[0];
    const int*   ei    = (const int*) d_in[1];
    const int*   batch = (const int*) d_in[2];
    const float *W1l = (const float*)d_in[3],  *b1l = (const float*)d_in[4],  *W1r = (const float*)d_in[5];
    const float *W2l = (const float*)d_in[6],  *b2l = (const float*)d_in[7],  *W2r = (const float*)d_in[8];
    const float *W3l = (const float*)d_in[9],  *b3l = (const float*)d_in[10], *W3r = (const float*)d_in[11];
    const float *lin1_w = (const float*)d_in[12], *lin1_b = (const float*)d_in[13];
    const float *g1 = (const float*)d_in[14], *be1 = (const float*)d_in[15];
    const float *lin2_w = (const float*)d_in[16], *lin2_b = (const float*)d_in[17];
    const float *g2 = (const float*)d_in[18], *be2 = (const float*)d_in[19];
    const float *lin3_w = (const float*)d_in[20], *lin3_b = (const float*)d_in[21];
    const float *g3 = (const float*)d_in[22], *be3 = (const float*)d_in[23];
    const float *lin4_w = (const float*)d_in[24], *lin4_b = (const float*)d_in[25];

    const int* srcp = ei;
    const int* dstp = ei + N_EDGES;

    // ---- workspace layout ----
    const long NF = (long)N_NODES * HD;              // 3,200,000
    char* wsb  = (char*)d_ws;
    int*  cnti = (int*)wsb;                          // 50,048
    int*  pos  = cnti + 50048;                       // 800,000
    int*  off  = pos  + 800000;                      // 50,056
    int*  nbr  = off  + 50056;                       // 800,000
    int*  bsum = nbr  + 800000;                      // 256
    bf16* B    = (bf16*)(bsum + 256);                // 3,200,000 bf16
    float* H1  = (float*)(B + NF);                   // 3,200,000
    float* H2  = H1  + NF;                           // 3,200,000
    float* cb  = H2  + NF;                           // 16,384
    float* m1  = cb  + NUM_GRAPHS * HD;              // 65,536
    float* m2  = m1  + NUM_GRAPHS * 256;             // 32,768
    float* endp= m2  + NUM_GRAPHS * 128;

    const size_t NEED = (size_t)((char*)endp - wsb);
    if (ws_size < NEED) {
        k_diag<<<(out_size + 255) / 256, 256, 0, stream>>>((float*)d_out, out_size,
                                                           (float)(ws_size >> 20));
        return;
    }

    const int TB = 256;
    const int gNE = (N_EDGES + TB - 1) / TB;
    const int gNF = (int)((NF + TB - 1) / TB);        // 12500
    const int gXB = (N_NODES + 31) / 32;              // 1563

    hipMemsetAsync(cnti, 0, 50048 * sizeof(int), stream);

    // ---- CSR build ----
    k_count<<<gNE, TB, 0, stream>>>(dstp, cnti, pos);
    k_scan1<<<SCAN_NB, TB, 0, stream>>>(cnti, off, bsum);
    k_scan3<<<SCAN_NB, TB, 0, stream>>>(off, bsum);
    k_fill<<<gNE, TB, 0, stream>>>(srcp, dstp, off, pos, nbr);

    // ---- SAGE layers (bf16 messages) ----
    k_xform3<IN_DIM><<<gXB, TB, 0, stream>>>(x, W1l, W1r, b1l, B, H1);
    k_gather<<<gNF, TB, 0, stream>>>(off, nbr, B, H1);
    k_xform3<HD><<<gXB, TB, 0, stream>>>(H1, W2l, W2r, b2l, B, H2);
    k_gather<<<gNF, TB, 0, stream>>>(off, nbr, B, H2);
    k_xform3<HD><<<gXB, TB, 0, stream>>>(H2, W3l, W3r, b3l, B, H1);
    k_gather<<<gNF, TB, 0, stream>>>(off, nbr, B, H1);

    // ---- pool + fused head (3 dispatches) ----
    k_pool2<<<NUM_GRAPHS, TB, 0, stream>>>(batch, H1, cb);
    k_linbn<256, 64><<<4, 1024, 0, stream>>>(cb, lin1_w, lin1_b, g1, be1, m1);
    k_linbn<128, 256><<<2, 1024, 0, stream>>>(m1, lin2_w, lin2_b, g2, be2, m2);
    k_linbn3f<<<1, 1024, 0, stream>>>(m2, lin3_w, lin3_b, g3, be3,
                                      lin4_w, lin4_b, (float*)d_out);
}

// Round 19
// 503.484 us; speedup vs baseline: 1.1827x; 1.1827x over previous
//
#include <hip/hip_runtime.h>
#include <hip/hip_bf16.h>

#define N_NODES   50000
#define N_EDGES   800000
#define NUM_GRAPHS 256
#define IN_DIM    128
#define HD        64
#define EPS       1e-5f
#define SCAN_NB   196      // ceil(50000/256)

typedef __hip_bfloat16 bf16;

// ---------------- diagnostics ----------------
__global__ void k_diag(float* __restrict__ out, int n, float v) {
    int t = blockIdx.x * 256 + threadIdx.x;
    if (t < n) out[t] = v;
}

// ---------------- CSR build ----------------
__global__ void k_count(const int* __restrict__ dst, int* __restrict__ cnti,
                        int* __restrict__ pos) {
    int e = blockIdx.x * 256 + threadIdx.x;
    if (e < N_EDGES) pos[e] = atomicAdd(&cnti[dst[e]], 1);
}

__global__ void k_scan1(const int* __restrict__ cnti, int* __restrict__ off,
                        int* __restrict__ bsum) {
    __shared__ int wsum[4];
    int idx = blockIdx.x * 256 + threadIdx.x;
    int lane = threadIdx.x & 63, wid = threadIdx.x >> 6;
    int v = (idx < N_NODES) ? cnti[idx] : 0;
    int s = v;
    #pragma unroll
    for (int o = 1; o < 64; o <<= 1) {
        int u = __shfl_up(s, o);
        if (lane >= o) s += u;
    }
    if (lane == 63) wsum[wid] = s;
    __syncthreads();
    int wbase = 0;
    #pragma unroll
    for (int w = 0; w < 4; w++) wbase += (w < wid) ? wsum[w] : 0;
    if (idx < N_NODES) off[idx] = wbase + s - v;
    if (threadIdx.x == 255) bsum[blockIdx.x] = wbase + s;
}

__global__ void k_scan3(int* __restrict__ off, const int* __restrict__ bsum) {
    __shared__ int wsum[4];
    __shared__ int spre;
    int lane = threadIdx.x & 63, wid = threadIdx.x >> 6;
    int v = (threadIdx.x < blockIdx.x) ? bsum[threadIdx.x] : 0;
    #pragma unroll
    for (int o = 32; o > 0; o >>= 1) v += __shfl_down(v, o);
    if (lane == 0) wsum[wid] = v;
    __syncthreads();
    if (threadIdx.x == 0) spre = wsum[0] + wsum[1] + wsum[2] + wsum[3];
    __syncthreads();
    int pre = spre;
    int idx = blockIdx.x * 256 + threadIdx.x;
    if (idx < N_NODES) off[idx] += pre;
    else if (idx == N_NODES) off[N_NODES] = N_EDGES;
}

__global__ void k_fill(const int* __restrict__ src, const int* __restrict__ dst,
                       const int* __restrict__ off, const int* __restrict__ pos,
                       int* __restrict__ nbr) {
    int e = blockIdx.x * 256 + threadIdx.x;
    if (e >= N_EDGES) return;
    int d = dst[e];
    nbr[off[d] + pos[e]] = src[e];
}

// ---- fused transform, LDS-staged X tile: B(bf16) = X@Wl ; C = X@Wr + bl ----
template <int K>
__global__ __launch_bounds__(256) void k_xform3(
        const float* __restrict__ X, const float* __restrict__ Wl,
        const float* __restrict__ Wr, const float* __restrict__ bl,
        bf16* __restrict__ B, float* __restrict__ C) {
    __shared__ float tile[32 * K];
    const int NPW = 8;
    int nodes0 = blockIdx.x * 32;
    {
        const int total4 = 32 * K / 4;
        int nmax4 = (N_NODES - nodes0) * K / 4;
        const float4* Xg = (const float4*)(X + (long)nodes0 * K);
        float4* tg = (float4*)tile;
        for (int idx = threadIdx.x; idx < total4; idx += 256) {
            float4 v = make_float4(0.f, 0.f, 0.f, 0.f);
            if (idx < nmax4) v = Xg[idx];
            tg[idx] = v;
        }
    }
    __syncthreads();
    int wave = threadIdx.x >> 6, j = threadIdx.x & 63;
    long base = (long)nodes0 + wave * NPW;
    if (base >= N_NODES) return;
    float accB[NPW], accC[NPW];
    #pragma unroll
    for (int n = 0; n < NPW; n++) { accB[n] = 0.f; accC[n] = 0.f; }
    const float* Xs = tile + (wave * NPW) * K;
    for (int kc = 0; kc < K; kc += 4) {
        float wl0 = Wl[(kc + 0) * HD + j], wr0 = Wr[(kc + 0) * HD + j];
        float wl1 = Wl[(kc + 1) * HD + j], wr1 = Wr[(kc + 1) * HD + j];
        float wl2 = Wl[(kc + 2) * HD + j], wr2 = Wr[(kc + 2) * HD + j];
        float wl3 = Wl[(kc + 3) * HD + j], wr3 = Wr[(kc + 3) * HD + j];
        #pragma unroll
        for (int n = 0; n < NPW; n++) {
            float4 xv = *(const float4*)(Xs + n * K + kc);
            accB[n] = fmaf(xv.x, wl0, accB[n]);
            accC[n] = fmaf(xv.x, wr0, accC[n]);
            accB[n] = fmaf(xv.y, wl1, accB[n]);
            accC[n] = fmaf(xv.y, wr1, accC[n]);
            accB[n] = fmaf(xv.z, wl2, accB[n]);
            accC[n] = fmaf(xv.z, wr2, accC[n]);
            accB[n] = fmaf(xv.w, wl3, accB[n]);
            accC[n] = fmaf(xv.w, wr3, accC[n]);
        }
    }
    float bb = bl[j];
    int nact = (int)min((long)NPW, (long)N_NODES - base);
    for (int n = 0; n < nact; n++) {
        long i = base + n;
        B[i * HD + j] = __float2bfloat16(accB[n]);
        C[i * HD + j] = accC[n] + bb;
    }
}

__device__ __forceinline__ float bflo(unsigned u) { return __uint_as_float(u << 16); }
__device__ __forceinline__ float bfhi(unsigned u) { return __uint_as_float(u & 0xffff0000u); }

// ---- CSR gather, pairwise (2 neighbor rows per wave-load):
// lanes 0-31 fetch neighbor tt, lanes 32-63 fetch tt+1; each lane = 2 cols (uint)
__global__ void k_gather(const int* __restrict__ off, const int* __restrict__ nbr,
                         const bf16* __restrict__ Bm, float* __restrict__ C) {
    int t = blockIdx.x * 256 + threadIdx.x;
    int i = t >> 6, lane = t & 63;
    if (i >= N_NODES) return;
    int half = lane >> 5, c = lane & 31;          // cols 2c, 2c+1
    const unsigned* B2 = (const unsigned*)Bm;     // B2[n*32 + c]
    int beg = off[i], end = off[i + 1];
    float e0 = 0.f, e1 = 0.f, e2 = 0.f, e3 = 0.f;
    float e4 = 0.f, e5 = 0.f, e6 = 0.f, e7 = 0.f;
    float o0 = 0.f, o1 = 0.f, o2 = 0.f, o3 = 0.f;
    float o4 = 0.f, o5 = 0.f, o6 = 0.f, o7 = 0.f;
    for (int base = beg; base < end; base += 64) {
        int idx = base + lane;
        int nv = (idx < end) ? nbr[idx] : 0;
        int m = min(64, end - base);
        int tt = 0;
        for (; tt + 16 <= m; tt += 16) {
            int n0 = __shfl(nv, tt + 0 + half);
            int n1 = __shfl(nv, tt + 2 + half);
            int n2 = __shfl(nv, tt + 4 + half);
            int n3 = __shfl(nv, tt + 6 + half);
            int n4 = __shfl(nv, tt + 8 + half);
            int n5 = __shfl(nv, tt + 10 + half);
            int n6 = __shfl(nv, tt + 12 + half);
            int n7 = __shfl(nv, tt + 14 + half);
            unsigned u0 = B2[(long)n0 * 32 + c];
            unsigned u1 = B2[(long)n1 * 32 + c];
            unsigned u2 = B2[(long)n2 * 32 + c];
            unsigned u3 = B2[(long)n3 * 32 + c];
            unsigned u4 = B2[(long)n4 * 32 + c];
            unsigned u5 = B2[(long)n5 * 32 + c];
            unsigned u6 = B2[(long)n6 * 32 + c];
            unsigned u7 = B2[(long)n7 * 32 + c];
            e0 += bflo(u0); o0 += bfhi(u0);
            e1 += bflo(u1); o1 += bfhi(u1);
            e2 += bflo(u2); o2 += bfhi(u2);
            e3 += bflo(u3); o3 += bfhi(u3);
            e4 += bflo(u4); o4 += bfhi(u4);
            e5 += bflo(u5); o5 += bfhi(u5);
            e6 += bflo(u6); o6 += bfhi(u6);
            e7 += bflo(u7); o7 += bfhi(u7);
        }
        for (; tt + 2 <= m; tt += 2) {
            int n0 = __shfl(nv, tt + half);
            unsigned u0 = B2[(long)n0 * 32 + c];
            e0 += bflo(u0); o0 += bfhi(u0);
        }
        if (tt < m) {   // odd leftover: only half 0 adds it
            int n0 = __shfl(nv, tt);
            if (half == 0) {
                unsigned u0 = B2[(long)n0 * 32 + c];
                e0 += bflo(u0); o0 += bfhi(u0);
            }
        }
    }
    float es = ((e0 + e1) + (e2 + e3)) + ((e4 + e5) + (e6 + e7));
    float os = ((o0 + o1) + (o2 + o3)) + ((o4 + o5) + (o6 + o7));
    es += __shfl(es, lane ^ 32);
    os += __shfl(os, lane ^ 32);
    if (half == 0) {
        int deg = end - beg;
        float inv = 1.0f / (float)max(deg, 1);
        float2* Cp = (float2*)(C + (long)i * HD + 2 * c);
        float2 cur = *Cp;
        cur.x += es * inv;
        cur.y += os * inv;
        *Cp = cur;
    }
}

// ---- global mean pool (bounds found in-block; sorted batch) ----
__global__ void k_pool2(const int* __restrict__ batch, const float* __restrict__ h,
                        float* __restrict__ cb) {
    __shared__ float red[4][64];
    __shared__ int sb[2];
    int g = blockIdx.x;
    if (threadIdx.x < 2) {
        int gq = g + threadIdx.x;
        int lo = 0, hi = N_NODES;
        while (lo < hi) {
            int mid = (lo + hi) >> 1;
            if (batch[mid] < gq) lo = mid + 1; else hi = mid;
        }
        sb[threadIdx.x] = lo;
    }
    __syncthreads();
    int beg = sb[0], end = sb[1];
    int j = threadIdx.x & 63, r = threadIdx.x >> 6;
    float s = 0.f;
    for (int n = beg + r; n < end; n += 4) s += h[(long)n * HD + j];
    red[r][j] = s;
    __syncthreads();
    if (r == 0) {
        float tot = (red[0][j] + red[1][j]) + (red[2][j] + red[3][j]);
        int cnt = end - beg;
        cb[g * HD + j] = tot / (float)max(cnt, 1);
    }
}

// ---- head GEMM: thread = 4 rows x 1 col, K unrolled x4, float4 A loads ----
template <int NN>
__global__ void k_head_gemm3(const float* __restrict__ A, const float* __restrict__ W,
                             const float* __restrict__ b, float* __restrict__ out,
                             int K) {
    int t = blockIdx.x * 256 + threadIdx.x;
    int j = t % NN;
    int r0 = (t / NN) * 4;
    float s0, s1, s2, s3;
    s0 = s1 = s2 = s3 = b[j];
    for (int k = 0; k < K; k += 4) {
        float w0 = W[(k + 0) * NN + j];
        float w1 = W[(k + 1) * NN + j];
        float w2 = W[(k + 2) * NN + j];
        float w3 = W[(k + 3) * NN + j];
        float4 a0 = *(const float4*)(A + (r0 + 0) * K + k);
        float4 a1 = *(const float4*)(A + (r0 + 1) * K + k);
        float4 a2 = *(const float4*)(A + (r0 + 2) * K + k);
        float4 a3 = *(const float4*)(A + (r0 + 3) * K + k);
        s0 = fmaf(a0.x, w0, s0); s0 = fmaf(a0.y, w1, s0); s0 = fmaf(a0.z, w2, s0); s0 = fmaf(a0.w, w3, s0);
        s1 = fmaf(a1.x, w0, s1); s1 = fmaf(a1.y, w1, s1); s1 = fmaf(a1.z, w2, s1); s1 = fmaf(a1.w, w3, s1);
        s2 = fmaf(a2.x, w0, s2); s2 = fmaf(a2.y, w1, s2); s2 = fmaf(a2.z, w2, s2); s2 = fmaf(a2.w, w3, s2);
        s3 = fmaf(a3.x, w0, s3); s3 = fmaf(a3.y, w1, s3); s3 = fmaf(a3.z, w2, s3); s3 = fmaf(a3.w, w3, s3);
    }
    out[(r0 + 0) * NN + j] = s0;
    out[(r0 + 1) * NN + j] = s1;
    out[(r0 + 2) * NN + j] = s2;
    out[(r0 + 3) * NN + j] = s3;
}

// ---- BN(train-stats)+tanh: block = 4 row-lanes x 64 cols, coalesced ----
__global__ void k_bn_tanh3(float* __restrict__ X, const float* __restrict__ g,
                           const float* __restrict__ be, int N) {
    __shared__ float ssum[4][64], ssq[4][64], sscale[64], smean[64];
    int j = blockIdx.x * 64 + (threadIdx.x & 63);
    int jj = threadIdx.x & 63, rl = threadIdx.x >> 6;
    float sum = 0.f, sq = 0.f;
    for (int r = rl; r < NUM_GRAPHS; r += 4) {
        float v = X[r * N + j];
        sum += v; sq += v * v;
    }
    ssum[rl][jj] = sum; ssq[rl][jj] = sq;
    __syncthreads();
    if (rl == 0) {
        float S = (ssum[0][jj] + ssum[1][jj]) + (ssum[2][jj] + ssum[3][jj]);
        float Q = (ssq[0][jj] + ssq[1][jj]) + (ssq[2][jj] + ssq[3][jj]);
        float mean = S * (1.0f / NUM_GRAPHS);
        float var = Q * (1.0f / NUM_GRAPHS) - mean * mean;
        smean[jj] = mean;
        sscale[jj] = rsqrtf(fmaxf(var, 0.f) + EPS) * g[j];
    }
    __syncthreads();
    float mean = smean[jj], scale = sscale[jj], sh = be[j];
    for (int r = rl; r < NUM_GRAPHS; r += 4) {
        float v = X[r * N + j];
        X[r * N + j] = tanhf((v - mean) * scale + sh);
    }
}

// final: out = A(256x64) @ W(64x10) + b
__global__ void k_final(const float* __restrict__ A, const float* __restrict__ W,
                        const float* __restrict__ b, float* __restrict__ out) {
    int t = blockIdx.x * 256 + threadIdx.x;
    if (t >= NUM_GRAPHS * 10) return;
    int i = t / 10, j = t % 10;
    float s = b[j];
    #pragma unroll
    for (int k = 0; k < 64; k++) s += A[i * 64 + k] * W[k * 10 + j];
    out[t] = s;
}

extern "C" void kernel_launch(void* const* d_in, const int* in_sizes, int n_in,
                              void* d_out, int out_size, void* d_ws, size_t ws_size,
                              hipStream_t stream) {
    const float* x     = (const float*)d_in[0];
    const int*   ei    = (const int*) d_in[1];
    const int*   batch = (const int*) d_in[2];
    const float *W1l = (const float*)d_in[3],  *b1l = (const float*)d_in[4],  *W1r = (const float*)d_in[5];
    const float *W2l = (const float*)d_in[6],  *b2l = (const float*)d_in[7],  *W2r = (const float*)d_in[8];
    const float *W3l = (const float*)d_in[9],  *b3l = (const float*)d_in[10], *W3r = (const float*)d_in[11];
    const float *lin1_w = (const float*)d_in[12], *lin1_b = (const float*)d_in[13];
    const float *g1 = (const float*)d_in[14], *be1 = (const float*)d_in[15];
    const float *lin2_w = (const float*)d_in[16], *lin2_b = (const float*)d_in[17];
    const float *g2 = (const float*)d_in[18], *be2 = (const float*)d_in[19];
    const float *lin3_w = (const float*)d_in[20], *lin3_b = (const float*)d_in[21];
    const float *g3 = (const float*)d_in[22], *be3 = (const float*)d_in[23];
    const float *lin4_w = (const float*)d_in[24], *lin4_b = (const float*)d_in[25];

    const int* srcp = ei;
    const int* dstp = ei + N_EDGES;

    // ---- workspace layout ----
    const long NF = (long)N_NODES * HD;              // 3,200,000
    char* wsb  = (char*)d_ws;
    int*  cnti = (int*)wsb;                          // 50,048
    int*  pos  = cnti + 50048;                       // 800,000
    int*  off  = pos  + 800000;                      // 50,056
    int*  nbr  = off  + 50056;                       // 800,000
    int*  bsum = nbr  + 800000;                      // 256
    bf16* B    = (bf16*)(bsum + 256);                // 3,200,000 bf16
    float* H1  = (float*)(B + NF);                   // 3,200,000
    float* H2  = H1  + NF;                           // 3,200,000
    float* cb  = H2  + NF;                           // 16,384
    float* m1  = cb  + NUM_GRAPHS * HD;              // 65,536
    float* m2  = m1  + NUM_GRAPHS * 256;             // 32,768
    float* m3  = m2  + NUM_GRAPHS * 128;             // 16,384
    float* endp= m3  + NUM_GRAPHS * 64;

    const size_t NEED = (size_t)((char*)endp - wsb);
    if (ws_size < NEED) {
        k_diag<<<(out_size + 255) / 256, 256, 0, stream>>>((float*)d_out, out_size,
                                                           (float)(ws_size >> 20));
        return;
    }

    const int TB = 256;
    const int gNE = (N_EDGES + TB - 1) / TB;
    const int gNF = (int)((NF + TB - 1) / TB);        // 12500
    const int gXB = (N_NODES + 31) / 32;              // 1563

    hipMemsetAsync(cnti, 0, 50048 * sizeof(int), stream);

    // ---- CSR build ----
    k_count<<<gNE, TB, 0, stream>>>(dstp, cnti, pos);
    k_scan1<<<SCAN_NB, TB, 0, stream>>>(cnti, off, bsum);
    k_scan3<<<SCAN_NB, TB, 0, stream>>>(off, bsum);
    k_fill<<<gNE, TB, 0, stream>>>(srcp, dstp, off, pos, nbr);

    // ---- SAGE layers (bf16 messages, pairwise gather) ----
    k_xform3<IN_DIM><<<gXB, TB, 0, stream>>>(x, W1l, W1r, b1l, B, H1);
    k_gather<<<gNF, TB, 0, stream>>>(off, nbr, B, H1);
    k_xform3<HD><<<gXB, TB, 0, stream>>>(H1, W2l, W2r, b2l, B, H2);
    k_gather<<<gNF, TB, 0, stream>>>(off, nbr, B, H2);
    k_xform3<HD><<<gXB, TB, 0, stream>>>(H2, W3l, W3r, b3l, B, H1);
    k_gather<<<gNF, TB, 0, stream>>>(off, nbr, B, H1);

    // ---- pool + head (R14/R17-proven kernels) ----
    k_pool2<<<NUM_GRAPHS, TB, 0, stream>>>(batch, H1, cb);
    k_head_gemm3<256><<<64, TB, 0, stream>>>(cb, lin1_w, lin1_b, m1, 64);
    k_bn_tanh3<<<4, TB, 0, stream>>>(m1, g1, be1, 256);
    k_head_gemm3<128><<<32, TB, 0, stream>>>(m1, lin2_w, lin2_b, m2, 256);
    k_bn_tanh3<<<2, TB, 0, stream>>>(m2, g2, be2, 128);
    k_head_gemm3<64><<<16, TB, 0, stream>>>(m2, lin3_w, lin3_b, m3, 128);
    k_bn_tanh3<<<1, TB, 0, stream>>>(m3, g3, be3, 64);
    k_final<<<(NUM_GRAPHS * 10 + TB - 1) / TB, TB, 0, stream>>>(m3, lin4_w, lin4_b, (float*)d_out);
}

// Round 20
// 469.375 us; speedup vs baseline: 1.2686x; 1.0727x over previous
//
#include <hip/hip_runtime.h>
#include <hip/hip_bf16.h>

#define N_NODES   50000
#define N_EDGES   800000
#define NUM_GRAPHS 256
#define IN_DIM    128
#define HD        64
#define EPS       1e-5f
#define SCAN_NB   196      // ceil(50000/256)

typedef __hip_bfloat16 bf16;

// ---------------- diagnostics ----------------
__global__ void k_diag(float* __restrict__ out, int n, float v) {
    int t = blockIdx.x * 256 + threadIdx.x;
    if (t < n) out[t] = v;
}

// ---------------- CSR build ----------------
__global__ void k_count(const int* __restrict__ dst, int* __restrict__ cnti,
                        int* __restrict__ pos) {
    int e = blockIdx.x * 256 + threadIdx.x;
    if (e < N_EDGES) pos[e] = atomicAdd(&cnti[dst[e]], 1);
}

__global__ void k_scan1(const int* __restrict__ cnti, int* __restrict__ off,
                        int* __restrict__ bsum) {
    __shared__ int wsum[4];
    int idx = blockIdx.x * 256 + threadIdx.x;
    int lane = threadIdx.x & 63, wid = threadIdx.x >> 6;
    int v = (idx < N_NODES) ? cnti[idx] : 0;
    int s = v;
    #pragma unroll
    for (int o = 1; o < 64; o <<= 1) {
        int u = __shfl_up(s, o);
        if (lane >= o) s += u;
    }
    if (lane == 63) wsum[wid] = s;
    __syncthreads();
    int wbase = 0;
    #pragma unroll
    for (int w = 0; w < 4; w++) wbase += (w < wid) ? wsum[w] : 0;
    if (idx < N_NODES) off[idx] = wbase + s - v;
    if (threadIdx.x == 255) bsum[blockIdx.x] = wbase + s;
}

__global__ void k_scan3(int* __restrict__ off, const int* __restrict__ bsum) {
    __shared__ int wsum[4];
    __shared__ int spre;
    int lane = threadIdx.x & 63, wid = threadIdx.x >> 6;
    int v = (threadIdx.x < blockIdx.x) ? bsum[threadIdx.x] : 0;
    #pragma unroll
    for (int o = 32; o > 0; o >>= 1) v += __shfl_down(v, o);
    if (lane == 0) wsum[wid] = v;
    __syncthreads();
    if (threadIdx.x == 0) spre = wsum[0] + wsum[1] + wsum[2] + wsum[3];
    __syncthreads();
    int pre = spre;
    int idx = blockIdx.x * 256 + threadIdx.x;
    if (idx < N_NODES) off[idx] += pre;
    else if (idx == N_NODES) off[N_NODES] = N_EDGES;
}

__global__ void k_fill(const int* __restrict__ src, const int* __restrict__ dst,
                       const int* __restrict__ off, const int* __restrict__ pos,
                       int* __restrict__ nbr) {
    int e = blockIdx.x * 256 + threadIdx.x;
    if (e >= N_EDGES) return;
    int d = dst[e];
    nbr[off[d] + pos[e]] = src[e];
}

// ---- fused transform, LDS-staged X tile: B(bf16) = X@Wl ; C = X@Wr + bl ----
template <int K>
__global__ __launch_bounds__(256) void k_xform3(
        const float* __restrict__ X, const float* __restrict__ Wl,
        const float* __restrict__ Wr, const float* __restrict__ bl,
        bf16* __restrict__ B, float* __restrict__ C) {
    __shared__ float tile[32 * K];
    const int NPW = 8;
    int nodes0 = blockIdx.x * 32;
    {
        const int total4 = 32 * K / 4;
        int nmax4 = (N_NODES - nodes0) * K / 4;
        const float4* Xg = (const float4*)(X + (long)nodes0 * K);
        float4* tg = (float4*)tile;
        for (int idx = threadIdx.x; idx < total4; idx += 256) {
            float4 v = make_float4(0.f, 0.f, 0.f, 0.f);
            if (idx < nmax4) v = Xg[idx];
            tg[idx] = v;
        }
    }
    __syncthreads();
    int wave = threadIdx.x >> 6, j = threadIdx.x & 63;
    long base = (long)nodes0 + wave * NPW;
    if (base >= N_NODES) return;
    float accB[NPW], accC[NPW];
    #pragma unroll
    for (int n = 0; n < NPW; n++) { accB[n] = 0.f; accC[n] = 0.f; }
    const float* Xs = tile + (wave * NPW) * K;
    for (int kc = 0; kc < K; kc += 4) {
        float wl0 = Wl[(kc + 0) * HD + j], wr0 = Wr[(kc + 0) * HD + j];
        float wl1 = Wl[(kc + 1) * HD + j], wr1 = Wr[(kc + 1) * HD + j];
        float wl2 = Wl[(kc + 2) * HD + j], wr2 = Wr[(kc + 2) * HD + j];
        float wl3 = Wl[(kc + 3) * HD + j], wr3 = Wr[(kc + 3) * HD + j];
        #pragma unroll
        for (int n = 0; n < NPW; n++) {
            float4 xv = *(const float4*)(Xs + n * K + kc);
            accB[n] = fmaf(xv.x, wl0, accB[n]);
            accC[n] = fmaf(xv.x, wr0, accC[n]);
            accB[n] = fmaf(xv.y, wl1, accB[n]);
            accC[n] = fmaf(xv.y, wr1, accC[n]);
            accB[n] = fmaf(xv.z, wl2, accB[n]);
            accC[n] = fmaf(xv.z, wr2, accC[n]);
            accB[n] = fmaf(xv.w, wl3, accB[n]);
            accC[n] = fmaf(xv.w, wr3, accC[n]);
        }
    }
    float bb = bl[j];
    int nact = (int)min((long)NPW, (long)N_NODES - base);
    for (int n = 0; n < nact; n++) {
        long i = base + n;
        B[i * HD + j] = __float2bfloat16(accB[n]);
        C[i * HD + j] = accC[n] + bb;
    }
}

__device__ __forceinline__ float bflo(unsigned u) { return __uint_as_float(u << 16); }
__device__ __forceinline__ float bfhi(unsigned u) { return __uint_as_float(u & 0xffff0000u); }

// ---- CSR gather, pairwise (2 neighbor rows per wave-load) ----
__global__ void k_gather(const int* __restrict__ off, const int* __restrict__ nbr,
                         const bf16* __restrict__ Bm, float* __restrict__ C) {
    int t = blockIdx.x * 256 + threadIdx.x;
    int i = t >> 6, lane = t & 63;
    if (i >= N_NODES) return;
    int half = lane >> 5, c = lane & 31;
    const unsigned* B2 = (const unsigned*)Bm;
    int beg = off[i], end = off[i + 1];
    float e0 = 0.f, e1 = 0.f, e2 = 0.f, e3 = 0.f;
    float e4 = 0.f, e5 = 0.f, e6 = 0.f, e7 = 0.f;
    float o0 = 0.f, o1 = 0.f, o2 = 0.f, o3 = 0.f;
    float o4 = 0.f, o5 = 0.f, o6 = 0.f, o7 = 0.f;
    for (int base = beg; base < end; base += 64) {
        int idx = base + lane;
        int nv = (idx < end) ? nbr[idx] : 0;
        int m = min(64, end - base);
        int tt = 0;
        for (; tt + 16 <= m; tt += 16) {
            int n0 = __shfl(nv, tt + 0 + half);
            int n1 = __shfl(nv, tt + 2 + half);
            int n2 = __shfl(nv, tt + 4 + half);
            int n3 = __shfl(nv, tt + 6 + half);
            int n4 = __shfl(nv, tt + 8 + half);
            int n5 = __shfl(nv, tt + 10 + half);
            int n6 = __shfl(nv, tt + 12 + half);
            int n7 = __shfl(nv, tt + 14 + half);
            unsigned u0 = B2[(long)n0 * 32 + c];
            unsigned u1 = B2[(long)n1 * 32 + c];
            unsigned u2 = B2[(long)n2 * 32 + c];
            unsigned u3 = B2[(long)n3 * 32 + c];
            unsigned u4 = B2[(long)n4 * 32 + c];
            unsigned u5 = B2[(long)n5 * 32 + c];
            unsigned u6 = B2[(long)n6 * 32 + c];
            unsigned u7 = B2[(long)n7 * 32 + c];
            e0 += bflo(u0); o0 += bfhi(u0);
            e1 += bflo(u1); o1 += bfhi(u1);
            e2 += bflo(u2); o2 += bfhi(u2);
            e3 += bflo(u3); o3 += bfhi(u3);
            e4 += bflo(u4); o4 += bfhi(u4);
            e5 += bflo(u5); o5 += bfhi(u5);
            e6 += bflo(u6); o6 += bfhi(u6);
            e7 += bflo(u7); o7 += bfhi(u7);
        }
        for (; tt + 2 <= m; tt += 2) {
            int n0 = __shfl(nv, tt + half);
            unsigned u0 = B2[(long)n0 * 32 + c];
            e0 += bflo(u0); o0 += bfhi(u0);
        }
        if (tt < m) {
            int n0 = __shfl(nv, tt);
            if (half == 0) {
                unsigned u0 = B2[(long)n0 * 32 + c];
                e0 += bflo(u0); o0 += bfhi(u0);
            }
        }
    }
    float es = ((e0 + e1) + (e2 + e3)) + ((e4 + e5) + (e6 + e7));
    float os = ((o0 + o1) + (o2 + o3)) + ((o4 + o5) + (o6 + o7));
    es += __shfl(es, lane ^ 32);
    os += __shfl(os, lane ^ 32);
    if (half == 0) {
        int deg = end - beg;
        float inv = 1.0f / (float)max(deg, 1);
        float2* Cp = (float2*)(C + (long)i * HD + 2 * c);
        float2 cur = *Cp;
        cur.x += es * inv;
        cur.y += os * inv;
        *Cp = cur;
    }
}

// ---- global mean pool (bounds found in-block; sorted batch) ----
__global__ void k_pool2(const int* __restrict__ batch, const float* __restrict__ h,
                        float* __restrict__ cb) {
    __shared__ float red[4][64];
    __shared__ int sb[2];
    int g = blockIdx.x;
    if (threadIdx.x < 2) {
        int gq = g + threadIdx.x;
        int lo = 0, hi = N_NODES;
        while (lo < hi) {
            int mid = (lo + hi) >> 1;
            if (batch[mid] < gq) lo = mid + 1; else hi = mid;
        }
        sb[threadIdx.x] = lo;
    }
    __syncthreads();
    int beg = sb[0], end = sb[1];
    int j = threadIdx.x & 63, r = threadIdx.x >> 6;
    float s = 0.f;
    for (int n = beg + r; n < end; n += 4) s += h[(long)n * HD + j];
    red[r][j] = s;
    __syncthreads();
    if (r == 0) {
        float tot = (red[0][j] + red[1][j]) + (red[2][j] + red[3][j]);
        int cnt = end - beg;
        cb[g * HD + j] = tot / (float)max(cnt, 1);
    }
}

// ---- fused linear+BN+tanh, LDS-staged A (K-chunked 64-col tiles) ----
// block = 1024 (64 cols x 16 rowgroups); grid = N/64
template <int N, int K>
__global__ __launch_bounds__(1024) void k_linbn_s(
        const float* __restrict__ A, const float* __restrict__ W,
        const float* __restrict__ b, const float* __restrict__ g,
        const float* __restrict__ be, float* __restrict__ out) {
    __shared__ float As[256 * 64];                 // 64 KB chunk: all rows x 64 K-cols
    __shared__ float ssum[16][64], ssq[16][64], sm[64], ssc[64];
    int jj = threadIdx.x & 63, rg = threadIdx.x >> 6;
    int j = blockIdx.x * 64 + jj;
    float vals[16];
    float bj = b[j];
    #pragma unroll
    for (int t = 0; t < 16; t++) vals[t] = bj;
    for (int k0 = 0; k0 < K; k0 += 64) {
        // stage A[:, k0:k0+64] -> As (coalesced float4)
        __syncthreads();
        {
            float4* As4 = (float4*)As;
            for (int q = threadIdx.x; q < 256 * 16; q += 1024) {
                int row = q >> 4, kq = q & 15;
                As4[q] = *(const float4*)(A + row * K + k0 + 4 * kq);
            }
        }
        __syncthreads();
        const float4* As4 = (const float4*)As;
        for (int kk4 = 0; kk4 < 16; kk4++) {
            int k = k0 + 4 * kk4;
            float w0 = W[(k + 0) * N + j];
            float w1 = W[(k + 1) * N + j];
            float w2 = W[(k + 2) * N + j];
            float w3 = W[(k + 3) * N + j];
            #pragma unroll
            for (int t = 0; t < 16; t++) {
                int r = rg + 16 * t;
                float4 a = As4[r * 16 + kk4];      // broadcast within wave
                vals[t] = fmaf(a.x, w0, vals[t]);
                vals[t] = fmaf(a.y, w1, vals[t]);
                vals[t] = fmaf(a.z, w2, vals[t]);
                vals[t] = fmaf(a.w, w3, vals[t]);
            }
        }
    }
    float sum = 0.f, sq = 0.f;
    #pragma unroll
    for (int t = 0; t < 16; t++) { sum += vals[t]; sq += vals[t] * vals[t]; }
    ssum[rg][jj] = sum; ssq[rg][jj] = sq;
    __syncthreads();
    if (rg == 0) {
        float S = 0.f, Q = 0.f;
        #pragma unroll
        for (int r = 0; r < 16; r++) { S += ssum[r][jj]; Q += ssq[r][jj]; }
        float mean = S * (1.0f / NUM_GRAPHS);
        float var = Q * (1.0f / NUM_GRAPHS) - mean * mean;
        sm[jj] = mean;
        ssc[jj] = rsqrtf(fmaxf(var, 0.f) + EPS) * g[j];
    }
    __syncthreads();
    float mean = sm[jj], sc = ssc[jj], sh = be[j];
    #pragma unroll
    for (int t = 0; t < 16; t++) {
        out[(rg + 16 * t) * N + j] = tanhf((vals[t] - mean) * sc + sh);
    }
}

// ---- lin3(128->64)+BN+tanh + lin4(64->10), single block, LDS-staged ----
__global__ __launch_bounds__(1024) void k_linbn3f_s(
        const float* __restrict__ A, const float* __restrict__ W,
        const float* __restrict__ b, const float* __restrict__ g,
        const float* __restrict__ be,
        const float* __restrict__ w4, const float* __restrict__ b4,
        float* __restrict__ out) {
    const int K = 128, N = 64;
    __shared__ float As[256 * 64];                 // 64 KB chunk
    __shared__ float m3s[256 * 65];                // 66.6 KB padded
    __shared__ float ssum[16][64], ssq[16][64], sm[64], ssc[64];
    int jj = threadIdx.x & 63, rg = threadIdx.x >> 6;
    int j = jj;
    float vals[16];
    float bj = b[j];
    #pragma unroll
    for (int t = 0; t < 16; t++) vals[t] = bj;
    for (int k0 = 0; k0 < K; k0 += 64) {
        __syncthreads();
        {
            float4* As4 = (float4*)As;
            for (int q = threadIdx.x; q < 256 * 16; q += 1024) {
                int row = q >> 4, kq = q & 15;
                As4[q] = *(const float4*)(A + row * K + k0 + 4 * kq);
            }
        }
        __syncthreads();
        const float4* As4 = (const float4*)As;
        for (int kk4 = 0; kk4 < 16; kk4++) {
            int k = k0 + 4 * kk4;
            float w0 = W[(k + 0) * N + j];
            float w1 = W[(k + 1) * N + j];
            float w2 = W[(k + 2) * N + j];
            float w3 = W[(k + 3) * N + j];
            #pragma unroll
            for (int t = 0; t < 16; t++) {
                int r = rg + 16 * t;
                float4 a = As4[r * 16 + kk4];
                vals[t] = fmaf(a.x, w0, vals[t]);
                vals[t] = fmaf(a.y, w1, vals[t]);
                vals[t] = fmaf(a.z, w2, vals[t]);
                vals[t] = fmaf(a.w, w3, vals[t]);
            }
        }
    }
    float sum = 0.f, sq = 0.f;
    #pragma unroll
    for (int t = 0; t < 16; t++) { sum += vals[t]; sq += vals[t] * vals[t]; }
    ssum[rg][jj] = sum; ssq[rg][jj] = sq;
    __syncthreads();
    if (rg == 0) {
        float S = 0.f, Q = 0.f;
        #pragma unroll
        for (int r = 0; r < 16; r++) { S += ssum[r][jj]; Q += ssq[r][jj]; }
        float mean = S * (1.0f / NUM_GRAPHS);
        float var = Q * (1.0f / NUM_GRAPHS) - mean * mean;
        sm[jj] = mean;
        ssc[jj] = rsqrtf(fmaxf(var, 0.f) + EPS) * g[j];
    }
    __syncthreads();
    float mean = sm[jj], sc = ssc[jj], sh = be[j];
    #pragma unroll
    for (int t = 0; t < 16; t++) {
        m3s[(rg + 16 * t) * 65 + jj] = tanhf((vals[t] - mean) * sc + sh);
    }
    __syncthreads();
    // lin4: thread i<256 computes row i's 10 outputs from LDS
    int i = threadIdx.x;
    if (i < NUM_GRAPHS) {
        const float* row = m3s + i * 65;
        #pragma unroll
        for (int jf = 0; jf < 10; jf++) {
            float s = b4[jf];
            #pragma unroll
            for (int k = 0; k < 64; k++) s = fmaf(row[k], w4[k * 10 + jf], s);
            out[i * 10 + jf] = s;
        }
    }
}

extern "C" void kernel_launch(void* const* d_in, const int* in_sizes, int n_in,
                              void* d_out, int out_size, void* d_ws, size_t ws_size,
                              hipStream_t stream) {
    const float* x     = (const float*)d_in[0];
    const int*   ei    = (const int*) d_in[1];
    const int*   batch = (const int*) d_in[2];
    const float *W1l = (const float*)d_in[3],  *b1l = (const float*)d_in[4],  *W1r = (const float*)d_in[5];
    const float *W2l = (const float*)d_in[6],  *b2l = (const float*)d_in[7],  *W2r = (const float*)d_in[8];
    const float *W3l = (const float*)d_in[9],  *b3l = (const float*)d_in[10], *W3r = (const float*)d_in[11];
    const float *lin1_w = (const float*)d_in[12], *lin1_b = (const float*)d_in[13];
    const float *g1 = (const float*)d_in[14], *be1 = (const float*)d_in[15];
    const float *lin2_w = (const float*)d_in[16], *lin2_b = (const float*)d_in[17];
    const float *g2 = (const float*)d_in[18], *be2 = (const float*)d_in[19];
    const float *lin3_w = (const float*)d_in[20], *lin3_b = (const float*)d_in[21];
    const float *g3 = (const float*)d_in[22], *be3 = (const float*)d_in[23];
    const float *lin4_w = (const float*)d_in[24], *lin4_b = (const float*)d_in[25];

    const int* srcp = ei;
    const int* dstp = ei + N_EDGES;

    // ---- workspace layout ----
    const long NF = (long)N_NODES * HD;              // 3,200,000
    char* wsb  = (char*)d_ws;
    int*  cnti = (int*)wsb;                          // 50,048
    int*  pos  = cnti + 50048;                       // 800,000
    int*  off  = pos  + 800000;                      // 50,056
    int*  nbr  = off  + 50056;                       // 800,000
    int*  bsum = nbr  + 800000;                      // 256
    bf16* B    = (bf16*)(bsum + 256);                // 3,200,000 bf16
    float* H1  = (float*)(B + NF);                   // 3,200,000
    float* H2  = H1  + NF;                           // 3,200,000
    float* cb  = H2  + NF;                           // 16,384
    float* m1  = cb  + NUM_GRAPHS * HD;              // 65,536
    float* m2  = m1  + NUM_GRAPHS * 256;             // 32,768
    float* endp= m2  + NUM_GRAPHS * 128;

    const size_t NEED = (size_t)((char*)endp - wsb);
    if (ws_size < NEED) {
        k_diag<<<(out_size + 255) / 256, 256, 0, stream>>>((float*)d_out, out_size,
                                                           (float)(ws_size >> 20));
        return;
    }

    const int TB = 256;
    const int gNE = (N_EDGES + TB - 1) / TB;
    const int gNF = (int)((NF + TB - 1) / TB);        // 12500
    const int gXB = (N_NODES + 31) / 32;              // 1563

    hipMemsetAsync(cnti, 0, 50048 * sizeof(int), stream);

    // ---- CSR build ----
    k_count<<<gNE, TB, 0, stream>>>(dstp, cnti, pos);
    k_scan1<<<SCAN_NB, TB, 0, stream>>>(cnti, off, bsum);
    k_scan3<<<SCAN_NB, TB, 0, stream>>>(off, bsum);
    k_fill<<<gNE, TB, 0, stream>>>(srcp, dstp, off, pos, nbr);

    // ---- SAGE layers (bf16 messages, pairwise gather) ----
    k_xform3<IN_DIM><<<gXB, TB, 0, stream>>>(x, W1l, W1r, b1l, B, H1);
    k_gather<<<gNF, TB, 0, stream>>>(off, nbr, B, H1);
    k_xform3<HD><<<gXB, TB, 0, stream>>>(H1, W2l, W2r, b2l, B, H2);
    k_gather<<<gNF, TB, 0, stream>>>(off, nbr, B, H2);
    k_xform3<HD><<<gXB, TB, 0, stream>>>(H2, W3l, W3r, b3l, B, H1);
    k_gather<<<gNF, TB, 0, stream>>>(off, nbr, B, H1);

    // ---- pool + fused head (LDS-staged A; 4 dispatches total) ----
    k_pool2<<<NUM_GRAPHS, TB, 0, stream>>>(batch, H1, cb);
    k_linbn_s<256, 64><<<4, 1024, 0, stream>>>(cb, lin1_w, lin1_b, g1, be1, m1);
    k_linbn_s<128, 256><<<2, 1024, 0, stream>>>(m1, lin2_w, lin2_b, g2, be2, m2);
    k_linbn3f_s<<<1, 1024, 0, stream>>>(m2, lin3_w, lin3_b, g3, be3,
                                        lin4_w, lin4_b, (float*)d_out);
}